// Round 4
// baseline (309.651 us; speedup 1.0000x reference)
//
#include <hip/hip_runtime.h>

using bf16x8 = __attribute__((ext_vector_type(8))) short;
using f32x4  = __attribute__((ext_vector_type(4))) float;

static constexpr int NN = 2048;   // nodes
static constexpr int NB = 32;     // batch
static constexpr int NC = 32;     // channels (C1 == C2)
static constexpr int GB = 16;     // batches per L3 chunk (A-chunk = 256 MB)

__device__ __forceinline__ unsigned short f2bf(float f) {
    unsigned int u = __float_as_uint(f);
    u += 0x7FFFu + ((u >> 16) & 1u);   // round-to-nearest-even
    return (unsigned short)(u >> 16);
}

// ---------------------------------------------------------------------------
// Projection: XWt[b][c][m] = bf16( sum_f X[b][m][f] * W[f][c] )   (no bias/relu)
// grid = (NN/256, nbatch), block = 256. One thread per node-row m.
// ---------------------------------------------------------------------------
template<int INCH>
__global__ void proj_kernel(const float* __restrict__ X, const float* __restrict__ W,
                            unsigned short* __restrict__ XWt)
{
    __shared__ float wlds[INCH * NC];
    const int b = blockIdx.y;
    const int m = blockIdx.x * 256 + threadIdx.x;
    for (int i = threadIdx.x; i < INCH * NC; i += 256) wlds[i] = W[i];
    __syncthreads();

    const float* xrow = X + ((size_t)b * NN + m) * INCH;
    float acc[NC];
#pragma unroll
    for (int c = 0; c < NC; ++c) acc[c] = 0.f;

    for (int f = 0; f < INCH; f += 4) {
        const float4 v = *reinterpret_cast<const float4*>(xrow + f);
        const float xv[4] = {v.x, v.y, v.z, v.w};
#pragma unroll
        for (int j = 0; j < 4; ++j) {
#pragma unroll
            for (int c = 0; c < NC; ++c)
                acc[c] += xv[j] * wlds[(f + j) * NC + c];
        }
    }

    unsigned short* outp = XWt + (size_t)b * NC * NN + m;
#pragma unroll
    for (int c = 0; c < NC; ++c) outp[(size_t)c * NN] = f2bf(acc[c]);
}

// ---------------------------------------------------------------------------
// GCN layer GEMM:  H = relu(A @ XW + bias),  A [NN x NN] fp32, XW^T bf16 [NC][NN].
// grid = (NN/64, nbatch), block = 256 (4 waves; each wave: 16 rows x 32 cols).
// Deep-prefetch K body: 128 floats (512B) per row per iteration, 8 dwordx4
// A-loads in flight (~4KB/wave) -> tolerates low occupancy in chunked mode.
// REV: map blockIdx.y -> nbatch-1-y (gemm2 re-reads the L3 chunk newest-first).
// WRITE_H=true : write H fp32 [b][n][NC]   (layer 1)
// WRITE_H=false: skip H, accumulate column sums into pooled[b][c]  (layer 2+pool)
// ---------------------------------------------------------------------------
template<bool WRITE_H, bool REV>
__global__ void gcn_gemm(const float* __restrict__ A, const unsigned short* __restrict__ Bt,
                         const float* __restrict__ bias, float* __restrict__ Hout,
                         float* __restrict__ pooled)
{
    const int b    = REV ? (gridDim.y - 1 - blockIdx.y) : blockIdx.y;
    const int wave = threadIdx.x >> 6;
    const int lane = threadIdx.x & 63;
    const int lr   = lane & 15;   // A-row / B-col / C-col index within tile
    const int kg   = lane >> 4;   // k-group (0..3), 8 k-elements each

    const int r0 = blockIdx.x * 64 + wave * 16;

    const float*          ap  = A  + ((size_t)b * NN + (r0 + lr)) * NN + kg * 8;
    const unsigned short* bp0 = Bt + ((size_t)b * NC + lr) * NN + kg * 8;
    const unsigned short* bp1 = bp0 + (size_t)16 * NN;

    f32x4 acc0 = {0.f, 0.f, 0.f, 0.f};
    f32x4 acc1 = {0.f, 0.f, 0.f, 0.f};

    for (int k = 0; k < NN; k += 128) {
        float4 xa[8];
        bf16x8 bb0[4], bb1[4];
#pragma unroll
        for (int s = 0; s < 4; ++s) {
            xa[2 * s]     = *reinterpret_cast<const float4*>(ap + s * 32);
            xa[2 * s + 1] = *reinterpret_cast<const float4*>(ap + s * 32 + 4);
            bb0[s] = *reinterpret_cast<const bf16x8*>(bp0 + s * 32);
            bb1[s] = *reinterpret_cast<const bf16x8*>(bp1 + s * 32);
        }
        ap += 128; bp0 += 128; bp1 += 128;

#pragma unroll
        for (int s = 0; s < 4; ++s) {
            bf16x8 af;
            af[0] = (short)f2bf(xa[2 * s].x); af[1] = (short)f2bf(xa[2 * s].y);
            af[2] = (short)f2bf(xa[2 * s].z); af[3] = (short)f2bf(xa[2 * s].w);
            af[4] = (short)f2bf(xa[2 * s + 1].x); af[5] = (short)f2bf(xa[2 * s + 1].y);
            af[6] = (short)f2bf(xa[2 * s + 1].z); af[7] = (short)f2bf(xa[2 * s + 1].w);

            acc0 = __builtin_amdgcn_mfma_f32_16x16x32_bf16(af, bb0[s], acc0, 0, 0, 0);
            acc1 = __builtin_amdgcn_mfma_f32_16x16x32_bf16(af, bb1[s], acc1, 0, 0, 0);
        }
    }

    const float bias0 = bias[lr];
    const float bias1 = bias[lr + 16];

    if constexpr (WRITE_H) {
#pragma unroll
        for (int j = 0; j < 4; ++j) {
            const int row = r0 + kg * 4 + j;
            float* hp = Hout + ((size_t)b * NN + row) * NC;
            hp[lr]      = fmaxf(acc0[j] + bias0, 0.f);
            hp[lr + 16] = fmaxf(acc1[j] + bias1, 0.f);
        }
    } else {
        float s0 = 0.f, s1 = 0.f;
#pragma unroll
        for (int j = 0; j < 4; ++j) {
            s0 += fmaxf(acc0[j] + bias0, 0.f);
            s1 += fmaxf(acc1[j] + bias1, 0.f);
        }
        // reduce over the 4 row-groups (lane bits 4,5): lanes with same lr share col
        s0 += __shfl_xor(s0, 16); s0 += __shfl_xor(s0, 32);
        s1 += __shfl_xor(s1, 16); s1 += __shfl_xor(s1, 32);
        if (kg == 0) {
            atomicAdd(&pooled[b * NC + lr],      s0);
            atomicAdd(&pooled[b * NC + 16 + lr], s1);
        }
    }
}

// ---------------------------------------------------------------------------
// FC head: out[b] = sum_h relu(pooled[b,:] @ Wf1[:,h] + bf1[h]) * Wf2[h] + bf2
// grid = NB blocks, 512 threads (one per hidden unit).
// ---------------------------------------------------------------------------
__global__ void head_kernel(const float* __restrict__ pooled,
                            const float* __restrict__ Wf1, const float* __restrict__ bf1,
                            const float* __restrict__ Wf2, const float* __restrict__ bf2,
                            float* __restrict__ out)
{
    const int b = blockIdx.x;
    const int h = threadIdx.x;   // 0..511

    float dot = 0.f;
#pragma unroll
    for (int c = 0; c < NC; ++c)
        dot += pooled[b * NC + c] * Wf1[c * 512 + h];

    const float v   = fmaxf(dot + bf1[h], 0.f);
    float part      = v * Wf2[h];

#pragma unroll
    for (int off = 32; off >= 1; off >>= 1)
        part += __shfl_xor(part, off);

    __shared__ float red[8];
    if ((threadIdx.x & 63) == 0) red[threadIdx.x >> 6] = part;
    __syncthreads();
    if (threadIdx.x == 0) {
        float s = 0.f;
#pragma unroll
        for (int i = 0; i < 8; ++i) s += red[i];
        out[b] = s + bf2[0];
    }
}

// ---------------------------------------------------------------------------
extern "C" void kernel_launch(void* const* d_in, const int* in_sizes, int n_in,
                              void* d_out, int out_size, void* d_ws, size_t ws_size,
                              hipStream_t stream)
{
    const float* x   = (const float*)d_in[0];
    const float* a   = (const float*)d_in[1];
    const float* W1  = (const float*)d_in[2];
    const float* b1  = (const float*)d_in[3];
    const float* W2  = (const float*)d_in[4];
    const float* b2  = (const float*)d_in[5];
    const float* Wf1 = (const float*)d_in[6];
    const float* bf1 = (const float*)d_in[7];
    const float* Wf2 = (const float*)d_in[8];
    const float* bf2 = (const float*)d_in[9];
    float* out = (float*)d_out;

    char* ws = (char*)d_ws;
    unsigned short* xwt1 = (unsigned short*)(ws);                    // 4 MB  [b][c][m] bf16
    float*          h1   = (float*)(ws + (4ull << 20));              // 8 MB  [b][m][c] fp32
    unsigned short* xwt2 = (unsigned short*)(ws + (12ull << 20));    // 4 MB  [b][c][m] bf16
    float*          pooled = (float*)(ws + (16ull << 20));           // 4 KB  [b][c] fp32

    hipMemsetAsync(pooled, 0, NB * NC * sizeof(float), stream);

    // projection for layer 1, all batches (X is small)
    proj_kernel<64><<<dim3(NN / 256, NB), 256, 0, stream>>>(x, W1, xwt1);

    // L3-chunked pipeline: gemm1 -> proj2 -> gemm2 per 16-batch chunk so that
    // gemm2 re-reads its 256MB A-chunk from Infinity Cache instead of HBM.
    for (int g = 0; g < NB / GB; ++g) {
        const size_t bo = (size_t)g * GB;
        const float*          Ag   = a    + bo * NN * NN;
        unsigned short*       x1g  = xwt1 + bo * NC * NN;
        float*                h1g  = h1   + bo * NN * NC;
        unsigned short*       x2g  = xwt2 + bo * NC * NN;
        float*                plg  = pooled + bo * NC;

        gcn_gemm<true, false><<<dim3(NN / 64, GB), 256, 0, stream>>>(
            Ag, x1g, b1, h1g, nullptr);

        proj_kernel<32><<<dim3(NN / 256, GB), 256, 0, stream>>>(h1g, W2, x2g);

        gcn_gemm<false, true><<<dim3(NN / 64, GB), 256, 0, stream>>>(
            Ag, x2g, b2, nullptr, plg);
    }

    head_kernel<<<dim3(NB), 512, 0, stream>>>(pooled, Wf1, bf1, Wf2, bf2, out);
}

// Round 5
// 289.647 us; speedup vs baseline: 1.0691x; 1.0691x over previous
//
#include <hip/hip_runtime.h>
#include <hip/hip_bf16.h>

using bf16x8 = __attribute__((ext_vector_type(8))) short;
using f32x4  = __attribute__((ext_vector_type(4))) float;

static constexpr int NN = 2048;   // nodes
static constexpr int NB = 32;     // batch
static constexpr int NC = 32;     // channels (C1 == C2)

__device__ __forceinline__ unsigned short f2bf(float f) {
    unsigned int u = __float_as_uint(f);
    u += 0x7FFFu + ((u >> 16) & 1u);   // round-to-nearest-even
    return (unsigned short)(u >> 16);
}

// ---------------------------------------------------------------------------
// Projection: XWt[b][c][m] = bf16( sum_f X[b][m][f] * W[f][c] )   (no bias/relu)
// grid = (NN/256, NB), block = 256. One thread per node-row m.
// ---------------------------------------------------------------------------
template<int INCH>
__global__ void proj_kernel(const float* __restrict__ X, const float* __restrict__ W,
                            unsigned short* __restrict__ XWt)
{
    __shared__ float wlds[INCH * NC];
    const int b = blockIdx.y;
    const int m = blockIdx.x * 256 + threadIdx.x;
    for (int i = threadIdx.x; i < INCH * NC; i += 256) wlds[i] = W[i];
    __syncthreads();

    const float* xrow = X + ((size_t)b * NN + m) * INCH;
    float acc[NC];
#pragma unroll
    for (int c = 0; c < NC; ++c) acc[c] = 0.f;

    for (int f = 0; f < INCH; f += 4) {
        const float4 v = *reinterpret_cast<const float4*>(xrow + f);
        const float xv[4] = {v.x, v.y, v.z, v.w};
#pragma unroll
        for (int j = 0; j < 4; ++j) {
#pragma unroll
            for (int c = 0; c < NC; ++c)
                acc[c] += xv[j] * wlds[(f + j) * NC + c];
        }
    }

    unsigned short* outp = XWt + (size_t)b * NC * NN + m;
#pragma unroll
    for (int c = 0; c < NC; ++c) outp[(size_t)c * NN] = f2bf(acc[c]);
}

// ---------------------------------------------------------------------------
// GCN layer GEMM:  H = relu(A @ XW + bias),  A [NN x NN] fp32, XW^T bf16 [NC][NN].
// grid = (NN/64, NB), block = 256 (4 waves; each wave: 16 rows x 32 cols).
// A is converted in-register via __float2bfloat16 so the compiler emits
// v_cvt_pk_bf16_f32 (hand-rolled bit-twiddle RNE was ~90 VALU ops/k-step and
// made the kernel VALU-bound at ~60% of HBM BW).
// REVK=true: walk K descending — gemm1 inserted A into the 256MB memory-side
// L3 in k-ascending order, so reverse order re-reads the freshest ~256MB as
// L3 hits (reading oldest-first at exact capacity = 0% hit, cf. round-4 null).
// WRITE_H=true : write H fp32 [b][n][NC]   (layer 1)
// WRITE_H=false: skip H, accumulate column sums into pooled[b][c]  (layer 2+pool)
// ---------------------------------------------------------------------------
template<bool WRITE_H, bool REVK>
__global__ void gcn_gemm(const float* __restrict__ A, const unsigned short* __restrict__ Bt,
                         const float* __restrict__ bias, float* __restrict__ Hout,
                         float* __restrict__ pooled)
{
    const int b    = blockIdx.y;
    const int wave = threadIdx.x >> 6;
    const int lane = threadIdx.x & 63;
    const int lr   = lane & 15;   // A-row / B-col / C-col index within tile
    const int kg   = lane >> 4;   // k-group (0..3), 8 k-elements each

    const int r0 = blockIdx.x * 64 + wave * 16;

    const float*          ap  = A  + ((size_t)b * NN + (r0 + lr)) * NN + kg * 8;
    const unsigned short* bp0 = Bt + ((size_t)b * NC + lr) * NN + kg * 8;
    const unsigned short* bp1 = bp0 + (size_t)16 * NN;

    f32x4 acc0 = {0.f, 0.f, 0.f, 0.f};
    f32x4 acc1 = {0.f, 0.f, 0.f, 0.f};

    union ABf { bf16x8 v; __hip_bfloat16 e[8]; };

    auto kstep = [&](int k) {
        const float4 x0 = *reinterpret_cast<const float4*>(ap + k);
        const float4 x1 = *reinterpret_cast<const float4*>(ap + k + 4);
        const bf16x8 bv0 = *reinterpret_cast<const bf16x8*>(bp0 + k);
        const bf16x8 bv1 = *reinterpret_cast<const bf16x8*>(bp1 + k);

        ABf af;
        af.e[0] = __float2bfloat16(x0.x); af.e[1] = __float2bfloat16(x0.y);
        af.e[2] = __float2bfloat16(x0.z); af.e[3] = __float2bfloat16(x0.w);
        af.e[4] = __float2bfloat16(x1.x); af.e[5] = __float2bfloat16(x1.y);
        af.e[6] = __float2bfloat16(x1.z); af.e[7] = __float2bfloat16(x1.w);

        acc0 = __builtin_amdgcn_mfma_f32_16x16x32_bf16(af.v, bv0, acc0, 0, 0, 0);
        acc1 = __builtin_amdgcn_mfma_f32_16x16x32_bf16(af.v, bv1, acc1, 0, 0, 0);
    };

    if constexpr (REVK) {
#pragma unroll 4
        for (int k = NN - 32; k >= 0; k -= 32) kstep(k);
    } else {
#pragma unroll 4
        for (int k = 0; k < NN; k += 32) kstep(k);
    }

    const float bias0 = bias[lr];
    const float bias1 = bias[lr + 16];

    if constexpr (WRITE_H) {
#pragma unroll
        for (int j = 0; j < 4; ++j) {
            const int row = r0 + kg * 4 + j;
            float* hp = Hout + ((size_t)b * NN + row) * NC;
            hp[lr]      = fmaxf(acc0[j] + bias0, 0.f);
            hp[lr + 16] = fmaxf(acc1[j] + bias1, 0.f);
        }
    } else {
        float s0 = 0.f, s1 = 0.f;
#pragma unroll
        for (int j = 0; j < 4; ++j) {
            s0 += fmaxf(acc0[j] + bias0, 0.f);
            s1 += fmaxf(acc1[j] + bias1, 0.f);
        }
        // reduce over the 4 row-groups (lane bits 4,5): lanes with same lr share col
        s0 += __shfl_xor(s0, 16); s0 += __shfl_xor(s0, 32);
        s1 += __shfl_xor(s1, 16); s1 += __shfl_xor(s1, 32);
        if (kg == 0) {
            atomicAdd(&pooled[b * NC + lr],      s0);
            atomicAdd(&pooled[b * NC + 16 + lr], s1);
        }
    }
}

// ---------------------------------------------------------------------------
// FC head: out[b] = sum_h relu(pooled[b,:] @ Wf1[:,h] + bf1[h]) * Wf2[h] + bf2
// grid = NB blocks, 512 threads (one per hidden unit).
// ---------------------------------------------------------------------------
__global__ void head_kernel(const float* __restrict__ pooled,
                            const float* __restrict__ Wf1, const float* __restrict__ bf1,
                            const float* __restrict__ Wf2, const float* __restrict__ bf2,
                            float* __restrict__ out)
{
    const int b = blockIdx.x;
    const int h = threadIdx.x;   // 0..511

    float dot = 0.f;
#pragma unroll
    for (int c = 0; c < NC; ++c)
        dot += pooled[b * NC + c] * Wf1[c * 512 + h];

    const float v   = fmaxf(dot + bf1[h], 0.f);
    float part      = v * Wf2[h];

#pragma unroll
    for (int off = 32; off >= 1; off >>= 1)
        part += __shfl_xor(part, off);

    __shared__ float red[8];
    if ((threadIdx.x & 63) == 0) red[threadIdx.x >> 6] = part;
    __syncthreads();
    if (threadIdx.x == 0) {
        float s = 0.f;
#pragma unroll
        for (int i = 0; i < 8; ++i) s += red[i];
        out[b] = s + bf2[0];
    }
}

// ---------------------------------------------------------------------------
extern "C" void kernel_launch(void* const* d_in, const int* in_sizes, int n_in,
                              void* d_out, int out_size, void* d_ws, size_t ws_size,
                              hipStream_t stream)
{
    const float* x   = (const float*)d_in[0];
    const float* a   = (const float*)d_in[1];
    const float* W1  = (const float*)d_in[2];
    const float* b1  = (const float*)d_in[3];
    const float* W2  = (const float*)d_in[4];
    const float* b2  = (const float*)d_in[5];
    const float* Wf1 = (const float*)d_in[6];
    const float* bf1 = (const float*)d_in[7];
    const float* Wf2 = (const float*)d_in[8];
    const float* bf2 = (const float*)d_in[9];
    float* out = (float*)d_out;

    char* ws = (char*)d_ws;
    unsigned short* xwt1 = (unsigned short*)(ws);                    // 4 MB  [b][c][m] bf16
    float*          h1   = (float*)(ws + (4ull << 20));              // 8 MB  [b][m][c] fp32
    unsigned short* xwt2 = (unsigned short*)(ws + (12ull << 20));    // 4 MB  [b][c][m] bf16
    float*          pooled = (float*)(ws + (16ull << 20));           // 4 KB  [b][c] fp32

    hipMemsetAsync(pooled, 0, NB * NC * sizeof(float), stream);

    proj_kernel<64><<<dim3(NN / 256, NB), 256, 0, stream>>>(x, W1, xwt1);

    gcn_gemm<true, false><<<dim3(NN / 64, NB), 256, 0, stream>>>(
        a, xwt1, b1, h1, nullptr);

    proj_kernel<32><<<dim3(NN / 256, NB), 256, 0, stream>>>(h1, W2, xwt2);

    gcn_gemm<false, true><<<dim3(NN / 64, NB), 256, 0, stream>>>(
        a, xwt2, b2, nullptr, pooled);

    head_kernel<<<dim3(NB), 512, 0, stream>>>(pooled, Wf1, bf1, Wf2, bf2, out);
}